// Round 7
// baseline (185.988 us; speedup 1.0000x reference)
//
#include <hip/hip_runtime.h>

#define NN 4096
#define DD 512
#define CP 128          // classes padded to 128 (pad classes: cnt=0, G=0 -> vanish)
#define MT 16           // rows per block
#define NB 256          // grid = 256 blocks = 256 CUs (1 block/CU via LDS -> co-resident)

// ws int/float word offsets (first 16 words zeroed by hipMemsetAsync each launch)
#define BAR0 0
#define BAR1 1
#define DONE 2
#define NEG  3
#define D_OFF    16
#define INVI_OFF (16 + NN)
#define CNTF_OFF (16 + 2*NN)
#define GB_OFF_W (16 + 2*NN + CP)   // byte 33344, 16B-aligned; bf16 G[CP][DD]

typedef __attribute__((ext_vector_type(8))) short bf16x8;
typedef __attribute__((ext_vector_type(4))) float f32x4;

static __device__ inline unsigned short f2bf(float f) {
    unsigned int u = __float_as_uint(f);
    unsigned int r = u + 0x7fffu + ((u >> 16) & 1u);   // round-to-nearest-even
    return (unsigned short)(r >> 16);
}

// Device-scope grid barrier. Safe: grid == 256 == #CUs, 146KB LDS forces
// 1 block/CU, so all blocks are co-resident; nothing retires before arriving.
static __device__ inline void gridbar(int* cnt) {
    __syncthreads();
    if (threadIdx.x == 0) {
        __threadfence();                       // release: write back dirty L2
        atomicAdd(cnt, 1);
        while (__hip_atomic_load(cnt, __ATOMIC_ACQUIRE, __HIP_MEMORY_SCOPE_AGENT) < NB)
            __builtin_amdgcn_s_sleep(2);
        __threadfence();                       // acquire: invalidate stale L1/L2
    }
    __syncthreads();
}

__global__ __launch_bounds__(256, 1) void fused(const float* __restrict__ img,
                                                const float* __restrict__ txt,
                                                const int* __restrict__ labels,
                                                float* __restrict__ ws,
                                                float* __restrict__ out) {
    __shared__ __align__(16) unsigned char As[MT * 1024];   // 16 KB  bf16 txtN tile (swizzled)
    __shared__ __align__(16) unsigned char Bs[CP * 1024];   // 128 KB bf16 G (swizzled)
    __shared__ int   wlist[4][64];
    __shared__ int   wcnt[4];
    __shared__ float cnts[CP];
    __shared__ float part[4][MT];
    __shared__ float Ss[MT];
    __shared__ float wred[4];
    __shared__ float sneg;
    __shared__ int   sdone;

    int t = threadIdx.x, w = t >> 6, l = t & 63;
    int b = blockIdx.x;
    int* wsi = (int*)ws;
    int row0 = b * MT;

    // ================= Phase A: 16 rows: norms, d_i, invi; bf16 txtN -> LDS As
    #pragma unroll
    for (int i = 0; i < 4; ++i) {
        int lr  = w * 4 + i;             // local row 0..15
        int row = row0 + lr;
        const float4* i4 = (const float4*)(img + (size_t)row * DD);
        const float4* t4 = (const float4*)(txt + (size_t)row * DD);
        float4 a0 = i4[l], a1 = i4[l + 64];
        float4 b0 = t4[l], b1 = t4[l + 64];
        float ssi = a0.x*a0.x + a0.y*a0.y + a0.z*a0.z + a0.w*a0.w
                  + a1.x*a1.x + a1.y*a1.y + a1.z*a1.z + a1.w*a1.w;
        float sst = b0.x*b0.x + b0.y*b0.y + b0.z*b0.z + b0.w*b0.w
                  + b1.x*b1.x + b1.y*b1.y + b1.z*b1.z + b1.w*b1.w;
        float dot = a0.x*b0.x + a0.y*b0.y + a0.z*b0.z + a0.w*b0.w
                  + a1.x*b1.x + a1.y*b1.y + a1.z*b1.z + a1.w*b1.w;
        #pragma unroll
        for (int o = 32; o >= 1; o >>= 1) {
            ssi += __shfl_xor(ssi, o);
            sst += __shfl_xor(sst, o);
            dot += __shfl_xor(dot, o);
        }
        float inv_t = rsqrtf(sst);
        ushort4 s0, s1;
        s0.x = f2bf(b0.x*inv_t); s0.y = f2bf(b0.y*inv_t);
        s0.z = f2bf(b0.z*inv_t); s0.w = f2bf(b0.w*inv_t);
        s1.x = f2bf(b1.x*inv_t); s1.y = f2bf(b1.y*inv_t);
        s1.z = f2bf(b1.z*inv_t); s1.w = f2bf(b1.w*inv_t);
        int swz = (lr & 7) << 4;
        *(ushort4*)&As[lr * 1024 + ((8 * l) ^ swz)]         = s0;   // k-cols 4l..
        *(ushort4*)&As[lr * 1024 + 512 + ((8 * l) ^ swz)]   = s1;   // k-cols 256+4l..
        if (l == 0) {
            float inv_i = rsqrtf(ssi);
            ws[D_OFF + row]    = dot * inv_i * inv_t;
            ws[INVI_OFF + row] = inv_i;
        }
    }
    gridbar(wsi + BAR0);

    // ================= Phase B: blocks 0..127 build G[c] (bf16) + cnt[c]
    if (b < CP) {
        int c = b;
        // 4-wave parallel ballot scan: wave w scans rows [w*1024, w*1024+1024)
        int cnt = 0;
        for (int it = 0; it < 16; ++it) {
            int row = (w << 10) + (it << 6) + l;
            int lab = labels[row];
            unsigned long long m = __ballot(lab == c);
            if (lab == c) {
                int pos = cnt + (int)__popcll(m & ((1ull << l) - 1ull));
                if (pos < 64) wlist[w][pos] = row;   // cap never binds (max ~28)
            }
            cnt += (int)__popcll(m);
        }
        if (l == 0) wcnt[w] = cnt < 64 ? cnt : 64;
        __syncthreads();
        int n0 = wcnt[0], n1 = wcnt[1], n2 = wcnt[2], n3 = wcnt[3];
        int n  = n0 + n1 + n2 + n3;
        int mx = n0 > n1 ? n0 : n1;
        if (n2 > mx) mx = n2;
        if (n3 > mx) mx = n3;
        // gather: thread t owns cols t and t+256; 4 independent segment chains
        float g0a=0.f,g0b=0.f,g0c=0.f,g0d=0.f, g1a=0.f,g1b=0.f,g1c=0.f,g1d=0.f;
        for (int i = 0; i < mx; ++i) {
            if (i < n0) { int j=wlist[0][i]; float wv=ws[INVI_OFF+j];
                g0a += img[(size_t)j*DD + t]*wv;       g1a += img[(size_t)j*DD + 256 + t]*wv; }
            if (i < n1) { int j=wlist[1][i]; float wv=ws[INVI_OFF+j];
                g0b += img[(size_t)j*DD + t]*wv;       g1b += img[(size_t)j*DD + 256 + t]*wv; }
            if (i < n2) { int j=wlist[2][i]; float wv=ws[INVI_OFF+j];
                g0c += img[(size_t)j*DD + t]*wv;       g1c += img[(size_t)j*DD + 256 + t]*wv; }
            if (i < n3) { int j=wlist[3][i]; float wv=ws[INVI_OFF+j];
                g0d += img[(size_t)j*DD + t]*wv;       g1d += img[(size_t)j*DD + 256 + t]*wv; }
        }
        unsigned short* gbf = (unsigned short*)(ws + GB_OFF_W);
        gbf[(size_t)c * DD + t]       = f2bf(g0a + g0b + g0c + g0d);
        gbf[(size_t)c * DD + 256 + t] = f2bf(g1a + g1b + g1c + g1d);
        if (t == 0) ws[CNTF_OFF + c] = (float)n;
    }
    gridbar(wsi + BAR1);

    // ================= Phase C: stage G -> Bs (swizzled), MFMA GEMM + epilogue
    if (t < CP) cnts[t] = ws[CNTF_OFF + t];
    {
        const int4* gB = (const int4*)(ws + GB_OFF_W);   // 128 rows x 64 int4
        int co = t & 63;                                  // int4 col (fixed)
        #pragma unroll 8
        for (int s = 0; s < 32; ++s) {
            int4 v = gB[s * 256 + t];
            int c = 4 * s + (t >> 6);
            *(int4*)&Bs[c * 1024 + ((co * 16) ^ ((c & 7) << 4))] = v;
        }
    }
    __syncthreads();

    f32x4 acc0 = {0.f,0.f,0.f,0.f}, acc1 = {0.f,0.f,0.f,0.f};
    int arow = l & 15, kq = l >> 4;
    int aswz = (arow & 7) << 4;
    int c0 = 32 * w;
    int cA = c0 + arow,      cB = cA + 16;
    int aoffA = cA * 1024,   aswzA = (cA & 7) << 4;
    int aoffB = cB * 1024,   aswzB = (cB & 7) << 4;
    #pragma unroll
    for (int ch = 0; ch < 16; ++ch) {
        int kb = ch * 64 + kq * 16;
        bf16x8 af = *(const bf16x8*)&As[arow * 1024 + (kb ^ aswz)];
        bf16x8 b0 = *(const bf16x8*)&Bs[aoffA + (kb ^ aswzA)];
        bf16x8 b1 = *(const bf16x8*)&Bs[aoffB + (kb ^ aswzB)];
        acc0 = __builtin_amdgcn_mfma_f32_16x16x32_bf16(af, b0, acc0, 0, 0, 0);
        acc1 = __builtin_amdgcn_mfma_f32_16x16x32_bf16(af, b1, acc1, 0, 0, 0);
    }

    // epilogue: S per row, then neg partial (R6-verified math)
    float rsum[4];
    #pragma unroll
    for (int r = 0; r < 4; ++r) {
        float s = acc0[r] + acc1[r];
        #pragma unroll
        for (int o = 1; o < 16; o <<= 1) s += __shfl_xor(s, o);
        rsum[r] = s;
    }
    if ((l & 15) == 0) {
        #pragma unroll
        for (int r = 0; r < 4; ++r) part[w][kq * 4 + r] = rsum[r];
    }
    __syncthreads();
    if (t < MT) Ss[t] = part[0][t] + part[1][t] + part[2][t] + part[3][t];
    __syncthreads();
    float p = 0.f;
    {
        float e0 = 0.f, e1 = 0.f;
        #pragma unroll
        for (int r = 0; r < 4; ++r) {
            e0 += __expf(Ss[kq * 4 + r] - acc0[r]);
            e1 += __expf(Ss[kq * 4 + r] - acc1[r]);
        }
        p = cnts[cA] * e0 + cnts[cB] * e1;
    }
    #pragma unroll
    for (int o = 32; o >= 1; o >>= 1) p += __shfl_xor(p, o);
    if (l == 0) wred[w] = p;
    __syncthreads();
    if (t == 0) {
        atomicAdd(ws + NEG, wred[0] + wred[1] + wred[2] + wred[3]);
        __threadfence();
        int old = atomicAdd(wsi + DONE, 1);
        sdone = (old == NB - 1);
        if (sdone) sneg = atomicAdd(ws + NEG, 0.0f);   // coherent read-back
    }
    __syncthreads();
    if (sdone) {
        __threadfence();   // defensive acquire before reading cross-block D
        float neg = sneg;
        float s = 0.f;
        #pragma unroll 4
        for (int i = t; i < NN; i += 256) {
            float dv = ws[D_OFF + i];
            s += logf(__expf(dv) + neg) - dv;
        }
        #pragma unroll
        for (int o = 32; o >= 1; o >>= 1) s += __shfl_xor(s, o);
        __syncthreads();
        if (l == 0) wred[w] = s;
        __syncthreads();
        if (t == 0) out[0] = wred[0] + wred[1] + wred[2] + wred[3];
    }
}

extern "C" void kernel_launch(void* const* d_in, const int* in_sizes, int n_in,
                              void* d_out, int out_size, void* d_ws, size_t ws_size,
                              hipStream_t stream) {
    const float* img  = (const float*)d_in[0];
    const float* txt  = (const float*)d_in[1];
    const int* labels = (const int*)d_in[2];
    float* ws  = (float*)d_ws;
    float* out = (float*)d_out;

    hipMemsetAsync(d_ws, 0, 64, stream);   // zero barrier/done/neg slots
    fused<<<NB, 256, 0, stream>>>(img, txt, labels, ws, out);
}

// Round 8
// 94.692 us; speedup vs baseline: 1.9641x; 1.9641x over previous
//
#include <hip/hip_runtime.h>

#define NN 4096
#define DD 512
#define CP 128          // classes padded to 128 (pad classes: cnt=0, G=0 -> vanish)
#define MT 16           // rows per kB block
#define NBB 256         // kB grid

// ws float-word offsets (first 16 words zeroed by hipMemsetAsync)
#define NEG   0
#define DONE  1
#define D_OFF 16
#define CNTF_OFF (16 + NN)
#define GB_OFF_W (16 + NN + CP)   // byte 16960, 16B-aligned; bf16 G[CP][DD]

typedef __attribute__((ext_vector_type(8))) short bf16x8;
typedef __attribute__((ext_vector_type(4))) float f32x4;

static __device__ inline unsigned short f2bf(float f) {
    unsigned int u = __float_as_uint(f);
    unsigned int r = u + 0x7fffu + ((u >> 16) & 1u);   // round-to-nearest-even
    return (unsigned short)(r >> 16);
}

// kA: one block per class (512 thr = 8 waves). Ballot-scan labels, compute
// member-row norms locally (wave-per-row), gather-accumulate G[c] in bf16.
// Depends only on inputs — no cross-kernel intermediates consumed.
__global__ __launch_bounds__(512) void kA(const float* __restrict__ img,
                                          const int* __restrict__ labels,
                                          float* __restrict__ ws) {
    __shared__ int   wlist[8][32];
    __shared__ int   wcnt[8];
    __shared__ int   soff[9];
    __shared__ int   flat[256];
    __shared__ float sinv[256];
    int c = blockIdx.x, t = threadIdx.x, w = t >> 6, l = t & 63;

    // scan: wave w scans rows [w*512, (w+1)*512)
    int cnt = 0;
    for (int it = 0; it < 8; ++it) {
        int row = (w << 9) + (it << 6) + l;
        int lab = labels[row];
        unsigned long long m = __ballot(lab == c);
        if (lab == c) {
            int pos = cnt + (int)__popcll(m & ((1ull << l) - 1ull));
            if (pos < 32) wlist[w][pos] = row;   // per-512-stripe cap, never binds
        }
        cnt += (int)__popcll(m);
    }
    if (l == 0) wcnt[w] = cnt < 32 ? cnt : 32;
    __syncthreads();
    if (t == 0) {
        int o = 0;
        #pragma unroll
        for (int i = 0; i < 8; ++i) { soff[i] = o; o += wcnt[i]; }
        soff[8] = o;
    }
    __syncthreads();
    int n = soff[8];
    for (int s = l; s < wcnt[w]; s += 64) flat[soff[w] + s] = wlist[w][s];
    __syncthreads();

    // norms: wave per row-slot (independent iterations -> pipelined loads)
    const float4* img4 = (const float4*)img;
    for (int s = w; s < n; s += 8) {
        int j = flat[s];
        float4 v0 = img4[(size_t)j * 128 + l];
        float4 v1 = img4[(size_t)j * 128 + 64 + l];
        float ss = v0.x*v0.x + v0.y*v0.y + v0.z*v0.z + v0.w*v0.w
                 + v1.x*v1.x + v1.y*v1.y + v1.z*v1.z + v1.w*v1.w;
        #pragma unroll
        for (int o = 32; o >= 1; o >>= 1) ss += __shfl_xor(ss, o);
        if (l == 0) sinv[s] = rsqrtf(ss);
    }
    __syncthreads();

    // gather: thread t owns column t (512 consecutive floats -> coalesced)
    float acc = 0.f;
    #pragma unroll 4
    for (int s = 0; s < n; ++s) {
        int j = flat[s];
        acc += img[(size_t)j * DD + t] * sinv[s];
    }
    unsigned short* gbf = (unsigned short*)(ws + GB_OFF_W);
    gbf[(size_t)c * DD + t] = f2bf(acc);
    if (t == 0) ws[CNTF_OFF + c] = (float)n;
}

// kB: 256 blocks x 16 rows, 1 block/CU (145KB LDS). Normalize txt on the fly
// (raw input -> bf16 LDS, no global txtN), write d_i; stage all of G into LDS
// in one burst; MFMA GEMM + exp/neg epilogue + done-counter finalize.
__global__ __launch_bounds__(256, 1) void kB(const float* __restrict__ img,
                                             const float* __restrict__ txt,
                                             float* __restrict__ ws,
                                             float* __restrict__ out) {
    __shared__ __align__(16) unsigned char As[MT * 1024];   // 16 KB  bf16 txtN tile (swizzled)
    __shared__ __align__(16) unsigned char Bs[CP * 1024];   // 128 KB bf16 G (swizzled)
    __shared__ float cnts[CP];
    __shared__ float part[4][MT];
    __shared__ float Ss[MT];
    __shared__ float wred[4];
    __shared__ float sneg;
    __shared__ int   sdone;

    int t = threadIdx.x, w = t >> 6, l = t & 63;
    int b = blockIdx.x;
    int row0 = b * MT;
    int* wsi = (int*)ws;

    // ---- Phase A: 16 rows: norms, d_i; normalized txt -> bf16 -> LDS As
    #pragma unroll
    for (int i = 0; i < 4; ++i) {
        int lr  = w * 4 + i;
        int row = row0 + lr;
        const float4* i4 = (const float4*)(img + (size_t)row * DD);
        const float4* t4 = (const float4*)(txt + (size_t)row * DD);
        float4 a0 = i4[l], a1 = i4[l + 64];
        float4 b0 = t4[l], b1 = t4[l + 64];
        float ssi = a0.x*a0.x + a0.y*a0.y + a0.z*a0.z + a0.w*a0.w
                  + a1.x*a1.x + a1.y*a1.y + a1.z*a1.z + a1.w*a1.w;
        float sst = b0.x*b0.x + b0.y*b0.y + b0.z*b0.z + b0.w*b0.w
                  + b1.x*b1.x + b1.y*b1.y + b1.z*b1.z + b1.w*b1.w;
        float dot = a0.x*b0.x + a0.y*b0.y + a0.z*b0.z + a0.w*b0.w
                  + a1.x*b1.x + a1.y*b1.y + a1.z*b1.z + a1.w*b1.w;
        #pragma unroll
        for (int o = 32; o >= 1; o >>= 1) {
            ssi += __shfl_xor(ssi, o);
            sst += __shfl_xor(sst, o);
            dot += __shfl_xor(dot, o);
        }
        float inv_t = rsqrtf(sst);
        ushort4 s0, s1;
        s0.x = f2bf(b0.x*inv_t); s0.y = f2bf(b0.y*inv_t);
        s0.z = f2bf(b0.z*inv_t); s0.w = f2bf(b0.w*inv_t);
        s1.x = f2bf(b1.x*inv_t); s1.y = f2bf(b1.y*inv_t);
        s1.z = f2bf(b1.z*inv_t); s1.w = f2bf(b1.w*inv_t);
        int swz = (lr & 7) << 4;
        *(ushort4*)&As[lr * 1024 + ((8 * l) ^ swz)]       = s0;
        *(ushort4*)&As[lr * 1024 + 512 + ((8 * l) ^ swz)] = s1;
        if (l == 0) {
            float inv_i = rsqrtf(ssi);
            ws[D_OFF + row] = dot * inv_i * inv_t;
        }
    }
    if (t < CP) cnts[t] = ws[CNTF_OFF + t];

    // ---- stage all of G -> Bs (swizzled), one deep burst
    {
        const int4* gB = (const int4*)(ws + GB_OFF_W);   // 128 rows x 64 int4
        int co = t & 63;
        #pragma unroll 8
        for (int s = 0; s < 32; ++s) {
            int4 v = gB[s * 256 + t];
            int c = 4 * s + (t >> 6);
            *(int4*)&Bs[c * 1024 + ((co * 16) ^ ((c & 7) << 4))] = v;
        }
    }
    __syncthreads();

    // ---- MFMA GEMM: R[16 x 128] for this block's rows
    f32x4 acc0 = {0.f,0.f,0.f,0.f}, acc1 = {0.f,0.f,0.f,0.f};
    int arow = l & 15, kq = l >> 4;
    int aswz = (arow & 7) << 4;
    int c0 = 32 * w;
    int cA = c0 + arow,    cB = cA + 16;
    int aoffA = cA * 1024, aswzA = (cA & 7) << 4;
    int aoffB = cB * 1024, aswzB = (cB & 7) << 4;
    #pragma unroll
    for (int ch = 0; ch < 16; ++ch) {
        int kb = ch * 64 + kq * 16;
        bf16x8 af = *(const bf16x8*)&As[arow * 1024 + (kb ^ aswz)];
        bf16x8 b0 = *(const bf16x8*)&Bs[aoffA + (kb ^ aswzA)];
        bf16x8 b1 = *(const bf16x8*)&Bs[aoffB + (kb ^ aswzB)];
        acc0 = __builtin_amdgcn_mfma_f32_16x16x32_bf16(af, b0, acc0, 0, 0, 0);
        acc1 = __builtin_amdgcn_mfma_f32_16x16x32_bf16(af, b1, acc1, 0, 0, 0);
    }

    // ---- epilogue: S per row, neg partial, block atomic (R7-verified math)
    float rsum[4];
    #pragma unroll
    for (int r = 0; r < 4; ++r) {
        float s = acc0[r] + acc1[r];
        #pragma unroll
        for (int o = 1; o < 16; o <<= 1) s += __shfl_xor(s, o);
        rsum[r] = s;
    }
    if ((l & 15) == 0) {
        #pragma unroll
        for (int r = 0; r < 4; ++r) part[w][kq * 4 + r] = rsum[r];
    }
    __syncthreads();
    if (t < MT) Ss[t] = part[0][t] + part[1][t] + part[2][t] + part[3][t];
    __syncthreads();
    float p;
    {
        float e0 = 0.f, e1 = 0.f;
        #pragma unroll
        for (int r = 0; r < 4; ++r) {
            e0 += __expf(Ss[kq * 4 + r] - acc0[r]);
            e1 += __expf(Ss[kq * 4 + r] - acc1[r]);
        }
        p = cnts[cA] * e0 + cnts[cB] * e1;
    }
    #pragma unroll
    for (int o = 32; o >= 1; o >>= 1) p += __shfl_xor(p, o);
    if (l == 0) wred[w] = p;
    __syncthreads();
    if (t == 0) {
        atomicAdd(ws + NEG, wred[0] + wred[1] + wred[2] + wred[3]);
        __threadfence();
        int old = atomicAdd(wsi + DONE, 1);
        sdone = (old == NBB - 1);
        if (sdone) sneg = atomicAdd(ws + NEG, 0.0f);   // coherent read-back
    }
    __syncthreads();
    if (sdone) {
        __threadfence();   // acquire before reading cross-block D
        float neg = sneg;
        float s = 0.f;
        #pragma unroll 4
        for (int i = t; i < NN; i += 256) {
            float dv = ws[D_OFF + i];
            s += logf(__expf(dv) + neg) - dv;
        }
        #pragma unroll
        for (int o = 32; o >= 1; o >>= 1) s += __shfl_xor(s, o);
        __syncthreads();
        if (l == 0) wred[w] = s;
        __syncthreads();
        if (t == 0) out[0] = wred[0] + wred[1] + wred[2] + wred[3];
    }
}

extern "C" void kernel_launch(void* const* d_in, const int* in_sizes, int n_in,
                              void* d_out, int out_size, void* d_ws, size_t ws_size,
                              hipStream_t stream) {
    const float* img  = (const float*)d_in[0];
    const float* txt  = (const float*)d_in[1];
    const int* labels = (const int*)d_in[2];
    float* ws  = (float*)d_ws;
    float* out = (float*)d_out;

    hipMemsetAsync(d_ws, 0, 64, stream);   // zero NEG/DONE
    kA<<<CP,  512, 0, stream>>>(img, labels, ws);
    kB<<<NBB, 256, 0, stream>>>(img, txt, ws, out);
}

// Round 10
// 94.367 us; speedup vs baseline: 1.9709x; 1.0034x over previous
//
#include <hip/hip_runtime.h>

#define NN 4096
#define DD 512
#define CP 128          // classes padded to 128 (pad classes: cnt=0, G=0 -> vanish)
#define MT 16           // rows per kB block
#define NBB 256         // kB grid
#define LROWS 64        // kA LDS-staged rows per class (tail handled from global)

// ws float-word offsets (NEG/DONE zeroed by kA block 0)
#define NEG   0
#define DONE  1
#define D_OFF 16
#define CNTF_OFF (16 + NN)
#define GB_OFF_W (16 + NN + CP)   // 16B-aligned; bf16 G[CP][DD]

typedef __attribute__((ext_vector_type(8))) short bf16x8;
typedef __attribute__((ext_vector_type(4))) float f32x4;

static __device__ inline unsigned short f2bf(float f) {
    unsigned int u = __float_as_uint(f);
    unsigned int r = u + 0x7fffu + ((u >> 16) & 1u);   // round-to-nearest-even
    return (unsigned short)(r >> 16);
}

// kA: one block per class (512 thr). Ballot-scan labels; stage member rows into
// LDS ONCE (each img row is read from HBM exactly once grid-wide); norms and
// gather both run from LDS. Tail rows (>LROWS, never expected) from global.
__global__ __launch_bounds__(512, 1) void kA(const float* __restrict__ img,
                                             const int* __restrict__ labels,
                                             float* __restrict__ ws) {
    __shared__ __align__(16) float lrows[LROWS * DD];   // 128 KB
    __shared__ int   wlist[8][32];
    __shared__ int   wcnt[8];
    __shared__ int   soff[9];
    __shared__ int   flat[256];
    __shared__ float sinv[256];
    int c = blockIdx.x, t = threadIdx.x, w = t >> 6, l = t & 63;

    if (c == 0 && t == 0) { ws[NEG] = 0.0f; ((int*)ws)[DONE] = 0; }

    // scan: wave w scans rows [w*512, (w+1)*512)
    int cnt = 0;
    for (int it = 0; it < 8; ++it) {
        int row = (w << 9) + (it << 6) + l;
        int lab = labels[row];
        unsigned long long m = __ballot(lab == c);
        if (lab == c) {
            int pos = cnt + (int)__popcll(m & ((1ull << l) - 1ull));
            if (pos < 32) wlist[w][pos] = row;   // per-stripe cap, never binds
        }
        cnt += (int)__popcll(m);
    }
    if (l == 0) wcnt[w] = cnt < 32 ? cnt : 32;
    __syncthreads();
    if (t == 0) {
        int o = 0;
        #pragma unroll
        for (int i = 0; i < 8; ++i) { soff[i] = o; o += wcnt[i]; }
        soff[8] = o;
    }
    __syncthreads();
    int n = soff[8];
    for (int s = l; s < wcnt[w]; s += 64) flat[soff[w] + s] = wlist[w][s];
    __syncthreads();

    int nl = n < LROWS ? n : LROWS;
    const float4* img4 = (const float4*)img;
    float4* lr4 = (float4*)lrows;

    // stage rows -> LDS (coalesced; 4 rows in flight across 512 threads)
    for (int idx = t; idx < nl * 128; idx += 512) {
        int r = idx >> 7, c4 = idx & 127;
        lr4[r * 128 + c4] = img4[(size_t)flat[r] * 128 + c4];
    }
    __syncthreads();

    // norms: wave per row-slot (LDS for staged rows, global for tail)
    for (int s = w; s < n; s += 8) {
        float4 v0, v1;
        if (s < nl) { v0 = lr4[s * 128 + l]; v1 = lr4[s * 128 + 64 + l]; }
        else { int j = flat[s]; v0 = img4[(size_t)j * 128 + l]; v1 = img4[(size_t)j * 128 + 64 + l]; }
        float ss = v0.x*v0.x + v0.y*v0.y + v0.z*v0.z + v0.w*v0.w
                 + v1.x*v1.x + v1.y*v1.y + v1.z*v1.z + v1.w*v1.w;
        #pragma unroll
        for (int o = 32; o >= 1; o >>= 1) ss += __shfl_xor(ss, o);
        if (l == 0) sinv[s] = rsqrtf(ss);
    }
    __syncthreads();

    // gather: thread t owns column t (LDS reads, conflict-free)
    float acc = 0.f;
    #pragma unroll 8
    for (int s = 0; s < nl; ++s) acc += lrows[s * DD + t] * sinv[s];
    for (int s = nl; s < n; ++s) acc += img[(size_t)flat[s] * DD + t] * sinv[s];

    unsigned short* gbf = (unsigned short*)(ws + GB_OFF_W);
    gbf[(size_t)c * DD + t] = f2bf(acc);
    if (t == 0) ws[CNTF_OFF + c] = (float)n;
}

// kB: 256 blocks x 16 rows, 1 block/CU (145KB LDS). Normalize txt on the fly,
// write d_i; stage all of G into LDS in one burst; MFMA GEMM + exp/neg epilogue
// + done-counter finalize. (R8-verified, absmax 0.)
__global__ __launch_bounds__(256, 1) void kB(const float* __restrict__ img,
                                             const float* __restrict__ txt,
                                             float* __restrict__ ws,
                                             float* __restrict__ out) {
    __shared__ __align__(16) unsigned char As[MT * 1024];   // 16 KB  bf16 txtN tile (swizzled)
    __shared__ __align__(16) unsigned char Bs[CP * 1024];   // 128 KB bf16 G (swizzled)
    __shared__ float cnts[CP];
    __shared__ float part[4][MT];
    __shared__ float Ss[MT];
    __shared__ float wred[4];
    __shared__ float sneg;
    __shared__ int   sdone;

    int t = threadIdx.x, w = t >> 6, l = t & 63;
    int b = blockIdx.x;
    int row0 = b * MT;
    int* wsi = (int*)ws;

    // ---- Phase A: 16 rows: norms, d_i; normalized txt -> bf16 -> LDS As
    #pragma unroll
    for (int i = 0; i < 4; ++i) {
        int lr  = w * 4 + i;
        int row = row0 + lr;
        const float4* i4 = (const float4*)(img + (size_t)row * DD);
        const float4* t4 = (const float4*)(txt + (size_t)row * DD);
        float4 a0 = i4[l], a1 = i4[l + 64];
        float4 b0 = t4[l], b1 = t4[l + 64];
        float ssi = a0.x*a0.x + a0.y*a0.y + a0.z*a0.z + a0.w*a0.w
                  + a1.x*a1.x + a1.y*a1.y + a1.z*a1.z + a1.w*a1.w;
        float sst = b0.x*b0.x + b0.y*b0.y + b0.z*b0.z + b0.w*b0.w
                  + b1.x*b1.x + b1.y*b1.y + b1.z*b1.z + b1.w*b1.w;
        float dot = a0.x*b0.x + a0.y*b0.y + a0.z*b0.z + a0.w*b0.w
                  + a1.x*b1.x + a1.y*b1.y + a1.z*b1.z + a1.w*b1.w;
        #pragma unroll
        for (int o = 32; o >= 1; o >>= 1) {
            ssi += __shfl_xor(ssi, o);
            sst += __shfl_xor(sst, o);
            dot += __shfl_xor(dot, o);
        }
        float inv_t = rsqrtf(sst);
        ushort4 s0, s1;
        s0.x = f2bf(b0.x*inv_t); s0.y = f2bf(b0.y*inv_t);
        s0.z = f2bf(b0.z*inv_t); s0.w = f2bf(b0.w*inv_t);
        s1.x = f2bf(b1.x*inv_t); s1.y = f2bf(b1.y*inv_t);
        s1.z = f2bf(b1.z*inv_t); s1.w = f2bf(b1.w*inv_t);
        int swz = (lr & 7) << 4;
        *(ushort4*)&As[lr * 1024 + ((8 * l) ^ swz)]       = s0;
        *(ushort4*)&As[lr * 1024 + 512 + ((8 * l) ^ swz)] = s1;
        if (l == 0) {
            float inv_i = rsqrtf(ssi);
            ws[D_OFF + row] = dot * inv_i * inv_t;
        }
    }
    if (t < CP) cnts[t] = ws[CNTF_OFF + t];

    // ---- stage all of G -> Bs (swizzled), one deep burst
    {
        const int4* gB = (const int4*)(ws + GB_OFF_W);   // 128 rows x 64 int4
        int co = t & 63;
        #pragma unroll 8
        for (int s = 0; s < 32; ++s) {
            int4 v = gB[s * 256 + t];
            int c = 4 * s + (t >> 6);
            *(int4*)&Bs[c * 1024 + ((co * 16) ^ ((c & 7) << 4))] = v;
        }
    }
    __syncthreads();

    // ---- MFMA GEMM: R[16 x 128] for this block's rows
    f32x4 acc0 = {0.f,0.f,0.f,0.f}, acc1 = {0.f,0.f,0.f,0.f};
    int arow = l & 15, kq = l >> 4;
    int aswz = (arow & 7) << 4;
    int c0 = 32 * w;
    int cA = c0 + arow,    cB = cA + 16;
    int aoffA = cA * 1024, aswzA = (cA & 7) << 4;
    int aoffB = cB * 1024, aswzB = (cB & 7) << 4;
    #pragma unroll
    for (int ch = 0; ch < 16; ++ch) {
        int kb = ch * 64 + kq * 16;
        bf16x8 af = *(const bf16x8*)&As[arow * 1024 + (kb ^ aswz)];
        bf16x8 b0 = *(const bf16x8*)&Bs[aoffA + (kb ^ aswzA)];
        bf16x8 b1 = *(const bf16x8*)&Bs[aoffB + (kb ^ aswzB)];
        acc0 = __builtin_amdgcn_mfma_f32_16x16x32_bf16(af, b0, acc0, 0, 0, 0);
        acc1 = __builtin_amdgcn_mfma_f32_16x16x32_bf16(af, b1, acc1, 0, 0, 0);
    }

    // ---- epilogue: S per row, neg partial, block atomic
    float rsum[4];
    #pragma unroll
    for (int r = 0; r < 4; ++r) {
        float s = acc0[r] + acc1[r];
        #pragma unroll
        for (int o = 1; o < 16; o <<= 1) s += __shfl_xor(s, o);
        rsum[r] = s;
    }
    if ((l & 15) == 0) {
        #pragma unroll
        for (int r = 0; r < 4; ++r) part[w][kq * 4 + r] = rsum[r];
    }
    __syncthreads();
    if (t < MT) Ss[t] = part[0][t] + part[1][t] + part[2][t] + part[3][t];
    __syncthreads();
    float p;
    {
        float e0 = 0.f, e1 = 0.f;
        #pragma unroll
        for (int r = 0; r < 4; ++r) {
            e0 += __expf(Ss[kq * 4 + r] - acc0[r]);
            e1 += __expf(Ss[kq * 4 + r] - acc1[r]);
        }
        p = cnts[cA] * e0 + cnts[cB] * e1;
    }
    #pragma unroll
    for (int o = 32; o >= 1; o >>= 1) p += __shfl_xor(p, o);
    if (l == 0) wred[w] = p;
    __syncthreads();
    if (t == 0) {
        atomicAdd(ws + NEG, wred[0] + wred[1] + wred[2] + wred[3]);
        __threadfence();
        int old = atomicAdd(wsi + DONE, 1);
        sdone = (old == NBB - 1);
        if (sdone) sneg = atomicAdd(ws + NEG, 0.0f);   // coherent read-back
    }
    __syncthreads();
    if (sdone) {
        __threadfence();   // acquire before reading cross-block D
        float neg = sneg;
        float s = 0.f;
        #pragma unroll 4
        for (int i = t; i < NN; i += 256) {
            float dv = ws[D_OFF + i];
            s += logf(__expf(dv) + neg) - dv;
        }
        #pragma unroll
        for (int o = 32; o >= 1; o >>= 1) s += __shfl_xor(s, o);
        __syncthreads();
        if (l == 0) wred[w] = s;
        __syncthreads();
        if (t == 0) out[0] = wred[0] + wred[1] + wred[2] + wred[3];
    }
}

extern "C" void kernel_launch(void* const* d_in, const int* in_sizes, int n_in,
                              void* d_out, int out_size, void* d_ws, size_t ws_size,
                              hipStream_t stream) {
    const float* img  = (const float*)d_in[0];
    const float* txt  = (const float*)d_in[1];
    const int* labels = (const int*)d_in[2];
    float* ws  = (float*)d_ws;
    float* out = (float*)d_out;

    kA<<<CP,  512, 0, stream>>>(img, labels, ws);
    kB<<<NBB, 256, 0, stream>>>(img, txt, ws, out);
}